// Round 10
// baseline (189.745 us; speedup 1.0000x reference)
//
#include <hip/hip_runtime.h>
#include <hip/hip_fp16.h>
#include <hip/hip_cooperative_groups.h>
#include <math.h>

namespace cg = cooperative_groups;

// Problem constants (from reference)
#define NQ 32768   // query points (pos1)
#define MC 8192    // source points (pos2)
#define CC 128     // channels
#define EPS_BN 1e-5f
#define EPS_D  1e-8

#define DBL_BIG 1e300
#define IDX_BIG 0x7fffffff

// KNN config (R15 verified structure, unchanged)
#define QB  64          // queries per block (2 tiles of 32)
#define TB  256         // threads per block (4 waves)
#define PCE 2048        // piece of M per block
#define NT  32          // 32-cand tiles per wave (1024 cands)
#define KM7 0xFFFFFF80u     // scan keys: keep sign+exp+16 mant, low 7 = (t<<2)|r
#define KMASK 0xFFFFE000u   // dump keys: sign+exp+10 mant, low 13 = cand index
#define IMASK 0x1FFFu       // 13-bit index (M=8192)
#define NSURV 48            // survivors/query (4 pieces x 2 wh x 2 h x 3)
#define KNN_B ((NQ / QB) * 4)   // 2048 scan blocks
#define GEMM_B (NQ / 64)        // 512
#define NGRP 8                  // stats atomic groups (2048 addresses)

typedef __attribute__((ext_vector_type(8))) short bf16x8;     // 8 bf16
typedef __attribute__((ext_vector_type(8))) _Float16 half8;   // 8 f16
typedef __attribute__((ext_vector_type(4))) float floatx4;    // 16x16 acc
typedef __attribute__((ext_vector_type(16))) float floatx16;  // 32x32 acc
typedef unsigned short ushort_t;

// RNE fp32 -> bf16 pair packed in u32 (lo = a, hi = b)
__device__ __forceinline__ unsigned bf16pair(float a, float b) {
    unsigned ua = __float_as_uint(a); ua = (ua + 0x7FFFu + ((ua >> 16) & 1u)) >> 16;
    unsigned ub = __float_as_uint(b); ub = (ub + 0x7FFFu + ((ub >> 16) & 1u)) >> 16;
    return ua | (ub << 16);
}
__device__ __forceinline__ ushort_t bf16one(float a) {
    unsigned ua = __float_as_uint(a);
    return (ushort_t)((ua + 0x7FFFu + ((ua >> 16) & 1u)) >> 16);
}
// unpack u32 = (lo bf16, hi bf16) -> 2 fp32
__device__ __forceinline__ float bflo(unsigned u) { return __uint_as_float(u << 16); }
__device__ __forceinline__ float bfhi(unsigned u) { return __uint_as_float(u & 0xFFFF0000u); }

// Branchless insert of x into ascending top-3: 1x v_min_f32 + 2x v_med3_f32.
__device__ __forceinline__ void ins3(float& k0, float& k1, float& k2, float x) {
    const float n0 = fminf(k0, x);
    const float n1 = __builtin_amdgcn_fmed3f(k0, k1, x);
    const float n2 = __builtin_amdgcn_fmed3f(k1, k2, x);
    k0 = n0; k1 = n1; k2 = n2;
}

// Single-instruction (d & m) | ir with the mask held in an SGPR.
__device__ __forceinline__ unsigned vandor(unsigned d, unsigned m, unsigned ir) {
    unsigned r;
    asm("v_and_or_b32 %0, %1, %2, %3" : "=v"(r) : "v"(d), "s"(m), "v"(ir));
    return r;
}

#define PK2(a, b) ((unsigned)__half_as_ushort(a) | ((unsigned)__half_as_ushort(b) << 16))

// ---------------------------------------------------------------------------
// Pack pos2 -> (a) 32x32x16 MFMA A-fragment tiles of split-f16 ext vectors,
//              (b) pos2f4: float4 {x,y,z,0} for the gemm rerank.
// ---------------------------------------------------------------------------
__global__ __launch_bounds__(TB) void pack_kernel(const float* __restrict__ pos2,
                                                  uint4* __restrict__ ptile,
                                                  float4* __restrict__ pos2f4) {
    const int c = blockIdx.x * TB + threadIdx.x;   // grid 32 x 256 = 8192
    const float x = pos2[c * 3 + 0];
    const float y = pos2[c * 3 + 1];
    const float z = pos2[c * 3 + 2];
    float4 p4; p4.x = x; p4.y = y; p4.z = z; p4.w = 0.f;
    pos2f4[c] = p4;
    const __half chx = __float2half(x); const float fchx = __half2float(chx);
    const __half chy = __float2half(y); const float fchy = __half2float(chy);
    const __half chz = __float2half(z); const float fchz = __half2float(chz);
    const __half clx = __float2half(x - fchx);
    const __half cly = __float2half(y - fchy);
    const __half clz = __float2half(z - fchz);
    const double X = (double)fchx + (double)__half2float(clx);
    const double Y = (double)fchy + (double)__half2float(cly);
    const double Z = (double)fchz + (double)__half2float(clz);
    const double hc = 0.5 * (X * X + Y * Y + Z * Z);
    const __half hchi = __float2half((float)hc);
    const __half hclo = __float2half((float)(hc - (double)__half2float(hchi)));
    const __half one = __float2half(1.0f);
    uint4 a0, a1;
    a0.x = PK2(chx, chy); a0.y = PK2(chz, clx); a0.z = PK2(cly, clz); a0.w = PK2(chx, chy);
    a1.x = PK2(chz, clx); a1.y = PK2(cly, clz); a1.z = PK2(hchi, hclo); a1.w = PK2(one, one);
    const int t = c >> 5, m = c & 31;
    ptile[(size_t)t * 64 + m]      = a0;   // k 0..7
    ptile[(size_t)t * 64 + 32 + m] = a1;   // k 8..15
    if (blockIdx.x == 0 && threadIdx.x < 128) {   // 2 zero pad tiles
        uint4 zf = {0u, 0u, 0u, 0u};
        ptile[(size_t)256 * 64 + threadIdx.x] = zf;
    }
}

// ---------------------------------------------------------------------------
// KNN scan (32x32 MFMA) + piggy-backed weight conversion + stats zero.
// (R15 verified, unchanged.)
// ---------------------------------------------------------------------------
__global__ __launch_bounds__(TB) void knn_kernel(const float* __restrict__ pos1,
                                                 const uint4* __restrict__ ptile,
                                                 unsigned* __restrict__ skeys,
                                                 const float* __restrict__ W0,
                                                 const float* __restrict__ W1,
                                                 const float* __restrict__ W2,
                                                 ushort_t* __restrict__ Wbf,
                                                 float* __restrict__ stats) {
    __shared__ __align__(16) ushort_t qext[QB][16];   // 2 KB query ext vectors

    if (blockIdx.x >= KNN_B) {                 // ---- prep blocks ----
        const int pb = blockIdx.x - KNN_B;     // 0..15
        const int f = pb * TB + threadIdx.x;   // float4 index within a layer
        const float* Ws[3] = {W0, W1, W2};
#pragma unroll
        for (int l = 0; l < 3; ++l) {
            const float4 v = ((const float4*)Ws[l])[f];
            unsigned* dst = (unsigned*)(Wbf + (size_t)l * CC * CC);
            dst[f * 2 + 0] = bf16pair(v.x, v.y);
            dst[f * 2 + 1] = bf16pair(v.z, v.w);
        }
        if (pb == 0)
            for (int i = threadIdx.x; i < 3 * NGRP * 256; i += TB) stats[i] = 0.f;
        return;
    }

    const int piece = blockIdx.x & 3;
    const int bq    = blockIdx.x >> 2;

    // ---- query ext staging ----
    if (threadIdx.x < QB) {
        const int qq = bq * QB + threadIdx.x;
        const float x = pos1[qq * 3 + 0];
        const float y = pos1[qq * 3 + 1];
        const float z = pos1[qq * 3 + 2];
        const __half phx = __float2half(x); const float fphx = __half2float(phx);
        const __half phy = __float2half(y); const float fphy = __half2float(phy);
        const __half phz = __float2half(z); const float fphz = __half2float(phz);
        const __half plx = __float2half(x - fphx);
        const __half ply = __float2half(y - fphy);
        const __half plz = __float2half(z - fphz);
        const double X = (double)fphx + (double)__half2float(plx);
        const double Y = (double)fphy + (double)__half2float(ply);
        const double Z = (double)fphz + (double)__half2float(plz);
        const double hp = 0.5 * (X * X + Y * Y + Z * Z);
        const __half hphi = __float2half((float)hp);
        const __half hplo = __float2half((float)(hp - (double)__half2float(hphi)));
        const ushort_t SG = 0x8000u;   // f16 sign flip = exact negation
        const ushort_t nx = (ushort_t)(__half_as_ushort(phx) ^ SG);
        const ushort_t ny = (ushort_t)(__half_as_ushort(phy) ^ SG);
        const ushort_t nz = (ushort_t)(__half_as_ushort(phz) ^ SG);
        const ushort_t mx = (ushort_t)(__half_as_ushort(plx) ^ SG);
        const ushort_t my = (ushort_t)(__half_as_ushort(ply) ^ SG);
        const ushort_t mz = (ushort_t)(__half_as_ushort(plz) ^ SG);
        const ushort_t on = __half_as_ushort(__float2half(1.0f));
        ushort_t* e = &qext[threadIdx.x][0];
        e[0] = nx; e[1] = ny; e[2] = nz; e[3] = nx; e[4]  = ny; e[5]  = nz;
        e[6] = mx; e[7] = my; e[8] = mz; e[9] = mx; e[10] = my; e[11] = mz;
        e[12] = on; e[13] = on;
        e[14] = __half_as_ushort(hphi); e[15] = __half_as_ushort(hplo);
    }
    __syncthreads();

    const int lane = threadIdx.x & 63;
    const int w    = threadIdx.x >> 6;
    const int qt   = w >> 1;            // query tile (0/1)
    const int wh   = w & 1;             // candidate half within piece
    const int col  = lane & 31;         // query column / candidate row
    const int h    = lane >> 5;         // k-slice (0/1)

    const uint4 bqu = *(const uint4*)&qext[qt * 32 + col][h * 8];
    const half8 bqh = *(const half8*)&bqu;

    const int cw = piece * PCE + wh * 1024;   // wave's candidate base
    const uint4* lp = ptile + (size_t)(cw >> 5) * 64 + h * 32 + col;
#define LD(t) lp[(size_t)(t) * 64]

    const float KINIT = __uint_as_float(0x7F000000u);   // large finite sentinel
    float a0 = KINIT, a1 = KINIT, a2 = KINIT;   // 4 independent top-3 chains
    float b0 = KINIT, b1 = KINIT, b2 = KINIT;
    float c0 = KINIT, c1 = KINIT, c2 = KINIT;
    float e0 = KINIT, e1 = KINIT, e2 = KINIT;
    unsigned i0 = 0u, i1 = 1u, i2 = 2u, i3 = 3u;
    const unsigned km7 = KM7;   // pinned to SGPR by the asm "s" constraint
    const floatx16 zc = {0.f,0.f,0.f,0.f,0.f,0.f,0.f,0.f,0.f,0.f,0.f,0.f,0.f,0.f,0.f,0.f};

#define KEY1(v, ir, K0, K1, K2) { \
        const unsigned u_ = vandor(__float_as_uint(v), km7, ir); \
        ins3(K0, K1, K2, __uint_as_float(u_)); }
#define KEYS(d) { \
        KEY1(d[0],  i0, a0, a1, a2); KEY1(d[1],  i1, a0, a1, a2); \
        KEY1(d[2],  i2, a0, a1, a2); KEY1(d[3],  i3, a0, a1, a2); \
        KEY1(d[4],  i0, b0, b1, b2); KEY1(d[5],  i1, b0, b1, b2); \
        KEY1(d[6],  i2, b0, b1, b2); KEY1(d[7],  i3, b0, b1, b2); \
        KEY1(d[8],  i0, c0, c1, c2); KEY1(d[9],  i1, c0, c1, c2); \
        KEY1(d[10], i2, c0, c1, c2); KEY1(d[11], i3, c0, c1, c2); \
        KEY1(d[12], i0, e0, e1, e2); KEY1(d[13], i1, e0, e1, e2); \
        KEY1(d[14], i2, e0, e1, e2); KEY1(d[15], i3, e0, e1, e2); \
        i0 += 4u; i1 += 4u; i2 += 4u; i3 += 4u; }

    uint4 LA = LD(0);
    uint4 LB = LD(1);
    for (int t = 0; t < NT; t += 2) {
        const floatx16 dv = __builtin_amdgcn_mfma_f32_32x32x16_f16(*(const half8*)&LA, bqh, zc, 0, 0, 0);
        LA = LD(t + 2);   // overshoots into pad tiles on last iter
        KEYS(dv);
        const floatx16 dw = __builtin_amdgcn_mfma_f32_32x32x16_f16(*(const half8*)&LB, bqh, zc, 0, 0, 0);
        LB = LD(t + 3);
        KEYS(dw);
    }
#undef LD
#undef KEYS
#undef KEY1

#define REKEY(kf, q) __uint_as_float((__float_as_uint(kf) & KMASK) | \
        (unsigned)(cw + (int)((__float_as_uint(kf) & 0x7Fu) >> 2) * 32 + \
                   (int)(__float_as_uint(kf) & 3u) + 8 * (q) + 4 * h))
    float m0 = KINIT, m1 = KINIT, m2 = KINIT;
    ins3(m0, m1, m2, REKEY(a0, 0)); ins3(m0, m1, m2, REKEY(a1, 0)); ins3(m0, m1, m2, REKEY(a2, 0));
    ins3(m0, m1, m2, REKEY(b0, 1)); ins3(m0, m1, m2, REKEY(b1, 1)); ins3(m0, m1, m2, REKEY(b2, 1));
    ins3(m0, m1, m2, REKEY(c0, 2)); ins3(m0, m1, m2, REKEY(c1, 2)); ins3(m0, m1, m2, REKEY(c2, 2));
    ins3(m0, m1, m2, REKEY(e0, 3)); ins3(m0, m1, m2, REKEY(e1, 3)); ins3(m0, m1, m2, REKEY(e2, 3));
#undef REKEY

    {
        const int q = bq * QB + qt * 32 + col;
        unsigned* dst = skeys + (size_t)q * NSURV + piece * 12 + wh * 6 + h * 3;
        dst[0] = __float_as_uint(m0);
        dst[1] = __float_as_uint(m1);
        dst[2] = __float_as_uint(m2);
    }
}

// ===========================================================================
// Shared device helpers for the GEMM side (used by fused and fallback paths)
// ===========================================================================

// Exact fp64 re-rank + interp staging into xa (bf16). Uses xa/wb as scratch.
__device__ __forceinline__ void rerank_interp_stage(
    const float* __restrict__ feat2, const unsigned* __restrict__ skeys,
    const float* __restrict__ pos1, const float4* __restrict__ pos2f4,
    int row0, short (*xa)[136], short (*wb)[136],
    int (*lidx)[3], float (*lw)[3], float* blk_s, float* blk_q)
{
    {   // exact fp64 re-rank of this block's 64 queries; 4 thr/query
        double* rrd = (double*)&xa[0][0];   // [64][4][3] = 6144 B scratch
        int*    rri = (int*)&wb[0][0];      // [64][4][3] = 3072 B scratch
        const int ql = threadIdx.x >> 2;
        const int pp = threadIdx.x & 3;
        const int qg = row0 + ql;
        const double qx = (double)pos1[qg * 3 + 0];
        const double qy = (double)pos1[qg * 3 + 1];
        const double qz = (double)pos1[qg * 3 + 2];
        double b0 = DBL_BIG, b1 = DBL_BIG, b2 = DBL_BIG;
        int    j0 = IDX_BIG, j1 = IDX_BIG, j2 = IDX_BIG;
        const uint4* kp = (const uint4*)(skeys + (size_t)qg * NSURV + pp * 12);
#pragma unroll
        for (int gi = 0; gi < 3; ++gi) {
            const uint4 kk = kp[gi];
            const unsigned ks[4] = {kk.x, kk.y, kk.z, kk.w};
#pragma unroll
            for (int u = 0; u < 4; ++u) {
                const int id = (int)(ks[u] & IMASK);
                const float4 cf = pos2f4[id];   // one aligned 16B load
                const double x = (double)cf.x;
                const double y = (double)cf.y;
                const double z = (double)cf.z;
                const double ax = qx - x, ay = qy - y, az = qz - z;
                const double d = ax * ax + ay * ay + az * az;
                const bool l2 = (d < b2) || (d == b2 && id < j2);
                if (l2) {
                    const bool l1 = (d < b1) || (d == b1 && id < j1);
                    const bool l0 = (d < b0) || (d == b0 && id < j0);
                    b2 = l1 ? b1 : d;              j2 = l1 ? j1 : id;
                    b1 = l1 ? (l0 ? b0 : d) : b1;  j1 = l1 ? (l0 ? j0 : id) : j1;
                    b0 = l0 ? d : b0;              j0 = l0 ? id : j0;
                }
            }
        }
        const int base = (ql * 4 + pp) * 3;
        rrd[base + 0] = b0; rri[base + 0] = j0;
        rrd[base + 1] = b1; rri[base + 1] = j1;
        rrd[base + 2] = b2; rri[base + 2] = j2;
        __syncthreads();
        if (threadIdx.x < QB) {
            const int qq = threadIdx.x;
            double c0 = DBL_BIG, c1 = DBL_BIG, c2 = DBL_BIG;
            int    i0 = IDX_BIG, i1 = IDX_BIG, i2 = IDX_BIG;
#pragma unroll
            for (int s = 0; s < 12; ++s) {
                const double d = rrd[qq * 12 + s];
                const int   id = rri[qq * 12 + s];
                const bool l2 = (d < c2) || (d == c2 && id < i2);
                if (l2) {
                    const bool l1 = (d < c1) || (d == c1 && id < i1);
                    const bool l0 = (d < c0) || (d == c0 && id < i0);
                    c2 = l1 ? c1 : d;              i2 = l1 ? i1 : id;
                    c1 = l1 ? (l0 ? c0 : d) : c1;  i1 = l1 ? (l0 ? i0 : id) : i1;
                    c0 = l0 ? d : c0;              i0 = l0 ? id : i0;
                }
            }
            const double r0 = 1.0 / (c0 + EPS_D);
            const double r1 = 1.0 / (c1 + EPS_D);
            const double r2 = 1.0 / (c2 + EPS_D);
            const double inv = 1.0 / (r0 + r1 + r2);
            lidx[qq][0] = i0; lidx[qq][1] = i1; lidx[qq][2] = i2;
            lw[qq][0] = (float)(r0 * inv);
            lw[qq][1] = (float)(r1 * inv);
            lw[qq][2] = (float)(r2 * inv);
        }
        __syncthreads();
    }
    if (threadIdx.x < CC) { blk_s[threadIdx.x] = 0.f; blk_q[threadIdx.x] = 0.f; }
#pragma unroll
    for (int e = threadIdx.x; e < 64 * 32; e += 256) {
        const int r = e >> 5, c4 = e & 31;
        const int i0 = lidx[r][0], i1 = lidx[r][1], i2 = lidx[r][2];
        const float w0 = lw[r][0], w1 = lw[r][1], w2 = lw[r][2];
        const float4 f0 = *(const float4*)&feat2[(size_t)i0 * CC + c4 * 4];
        const float4 f1 = *(const float4*)&feat2[(size_t)i1 * CC + c4 * 4];
        const float4 f2 = *(const float4*)&feat2[(size_t)i2 * CC + c4 * 4];
        float4 v;
        v.x = w0 * f0.x + w1 * f1.x + w2 * f2.x;
        v.y = w0 * f0.y + w1 * f1.y + w2 * f2.y;
        v.z = w0 * f0.z + w1 * f1.z + w2 * f2.z;
        v.w = w0 * f0.w + w1 * f1.w + w2 * f2.w;
        unsigned* dst = (unsigned*)&xa[r][0];
        dst[c4 * 2 + 0] = bf16pair(v.x, v.y);
        dst[c4 * 2 + 1] = bf16pair(v.z, v.w);
    }
}

// Reduce 8-group stats -> BN scale/shift in LDS; zero block stat accums.
__device__ __forceinline__ void bn_reduce_lds(const float* __restrict__ statsIn,
                                              const float* __restrict__ g,
                                              const float* __restrict__ be,
                                              float* sc_l, float* sh_l,
                                              float* blk_s, float* blk_q)
{
    if (threadIdx.x < CC) {
        const int c = threadIdx.x;
        float s = 0.f, q = 0.f;
#pragma unroll
        for (int gr = 0; gr < NGRP; ++gr) {
            s += statsIn[gr * 256 + c];
            q += statsIn[gr * 256 + CC + c];
        }
        const float m = s * (1.f / (float)NQ);
        const float v = fmaf(-m, m, q * (1.f / (float)NQ));
        const float rstd = rsqrtf(v + EPS_BN);
        const float scl = g[c] * rstd;
        sc_l[c] = scl;
        sh_l[c] = fmaf(-m, scl, be[c]);
        blk_s[c] = 0.f; blk_q[c] = 0.f;
    }
}

// Apply BN+ReLU in place to the LDS activation tile (bf16).
__device__ __forceinline__ void bn_relu_xa(short (*xa)[136],
                                           const float* sc_l, const float* sh_l)
{
#pragma unroll
    for (int e = threadIdx.x; e < 64 * 16; e += 256) {
        const int r = e >> 4, c8 = e & 15;
        const uint4 u = *(const uint4*)&xa[r][c8 * 8];
        const float4 s0 = *(const float4*)&sc_l[c8 * 8];
        const float4 s1 = *(const float4*)&sc_l[c8 * 8 + 4];
        const float4 h0 = *(const float4*)&sh_l[c8 * 8];
        const float4 h1 = *(const float4*)&sh_l[c8 * 8 + 4];
        const float v0 = fmaxf(fmaf(bflo(u.x), s0.x, h0.x), 0.f);
        const float v1 = fmaxf(fmaf(bfhi(u.x), s0.y, h0.y), 0.f);
        const float v2 = fmaxf(fmaf(bflo(u.y), s0.z, h0.z), 0.f);
        const float v3 = fmaxf(fmaf(bfhi(u.y), s0.w, h0.w), 0.f);
        const float v4 = fmaxf(fmaf(bflo(u.z), s1.x, h1.x), 0.f);
        const float v5 = fmaxf(fmaf(bfhi(u.z), s1.y, h1.y), 0.f);
        const float v6 = fmaxf(fmaf(bflo(u.w), s1.z, h1.z), 0.f);
        const float v7 = fmaxf(fmaf(bfhi(u.w), s1.w, h1.w), 0.f);
        uint4 o;
        o.x = bf16pair(v0, v1); o.y = bf16pair(v2, v3);
        o.z = bf16pair(v4, v5); o.w = bf16pair(v6, v7);
        *(uint4*)&xa[r][c8 * 8] = o;
    }
}

// One MFMA layer on the LDS-resident X tile: stage W, GEMM, write result
// (bias-added, bf16) back into xa, accumulate column stats into statsOut.
__device__ __forceinline__ void layer_mfma_xa(short (*xa)[136], short (*wb)[136],
                                              float* blk_s, float* blk_q,
                                              const ushort_t* __restrict__ Wb,
                                              const float* __restrict__ bias,
                                              float* __restrict__ statsOut)
{
#pragma unroll
    for (int e = threadIdx.x; e < 128 * 16; e += 256) {
        const int co = e >> 4, seg = e & 15;
        *(float4*)&wb[co][seg * 8] = *(const float4*)&Wb[(size_t)co * CC + seg * 8];
    }
    __syncthreads();

    const int lane = threadIdx.x & 63;
    const int wv = threadIdx.x >> 6;
    const int nn = lane & 15;
    const int quad = lane >> 4;

    floatx4 acc[8] = {};
    const short* arow = &xa[wv * 16 + nn][0];
#pragma unroll
    for (int ks = 0; ks < 4; ++ks) {
        const bf16x8 a = *(const bf16x8*)(arow + ks * 32 + quad * 8);
#pragma unroll
        for (int ct = 0; ct < 8; ++ct) {
            const bf16x8 b = *(const bf16x8*)(&wb[ct * 16 + nn][0] + ks * 32 + quad * 8);
            acc[ct] = __builtin_amdgcn_mfma_f32_16x16x32_bf16(a, b, acc[ct], 0, 0, 0);
        }
    }
    __syncthreads();   // drain all xa reads before overwriting in place
#pragma unroll
    for (int ct = 0; ct < 8; ++ct) {
        const float bv = bias[ct * 16 + nn];
        float s = 0.f, qv = 0.f;
#pragma unroll
        for (int r = 0; r < 4; ++r) {
            acc[ct][r] += bv;
            s += acc[ct][r];
            qv = fmaf(acc[ct][r], acc[ct][r], qv);
        }
#pragma unroll
        for (int r = 0; r < 4; ++r)
            xa[wv * 16 + quad * 4 + r][ct * 16 + nn] = (short)bf16one(acc[ct][r]);
        s += __shfl_xor(s, 16, 64); s += __shfl_xor(s, 32, 64);
        qv += __shfl_xor(qv, 16, 64); qv += __shfl_xor(qv, 32, 64);
        if (quad == 0) {
            atomicAdd(&blk_s[ct * 16 + nn], s);
            atomicAdd(&blk_q[ct * 16 + nn], qv);
        }
    }
    __syncthreads();
    {
        const int ch = threadIdx.x;
        const float v = (ch < CC) ? blk_s[ch] : blk_q[ch - CC];
        atomicAdd(&statsOut[(blockIdx.x & (NGRP - 1)) * 256 + ch], v);
    }
}

// ---------------------------------------------------------------------------
// Fused MLP chain (cooperative): rerank+interp+L0 -> sync -> BN+L1 -> sync ->
// BN+L2 -> sync -> BN-final -> out. Activation tile stays in LDS throughout.
// grid = 512 x 256 (2 blocks/CU co-resident; LDS ~54.5 KB).
// ---------------------------------------------------------------------------
__global__ __launch_bounds__(256) void gemm_fused(
        const float* __restrict__ feat2, const unsigned* __restrict__ skeys,
        const float* __restrict__ pos1, const float4* __restrict__ pos2f4,
        const ushort_t* __restrict__ Wbf,
        const float* __restrict__ b0_, const float* __restrict__ b1_, const float* __restrict__ b2_,
        const float* __restrict__ g0_, const float* __restrict__ g1_, const float* __restrict__ g2_,
        const float* __restrict__ be0_, const float* __restrict__ be1_, const float* __restrict__ be2_,
        float* __restrict__ st0, float* __restrict__ st1, float* __restrict__ st2,
        float* __restrict__ out)
{
    __shared__ __align__(16) short xa[64][136];
    __shared__ __align__(16) short wb[128][136];
    __shared__ __align__(16) float blk_s[CC], blk_q[CC];
    __shared__ __align__(16) float sc_l[CC], sh_l[CC];
    __shared__ int   lidx[QB][3];
    __shared__ float lw[QB][3];

    cg::grid_group grid = cg::this_grid();
    const int row0 = blockIdx.x * 64;

    // ---- phase 0: rerank + interp -> xa; GEMM layer 0 -> xa, st0 ----
    rerank_interp_stage(feat2, skeys, pos1, pos2f4, row0, xa, wb, lidx, lw, blk_s, blk_q);
    layer_mfma_xa(xa, wb, blk_s, blk_q, Wbf + 0 * CC * CC, b0_, st0);
    grid.sync();

    // ---- phase 1: BN(st0) + ReLU on xa; GEMM layer 1 -> xa, st1 ----
    bn_reduce_lds(st0, g0_, be0_, sc_l, sh_l, blk_s, blk_q);
    __syncthreads();
    bn_relu_xa(xa, sc_l, sh_l);
    __syncthreads();
    layer_mfma_xa(xa, wb, blk_s, blk_q, Wbf + 1 * CC * CC, b1_, st1);
    grid.sync();

    // ---- phase 2: BN(st1) + ReLU; GEMM layer 2 -> xa, st2 ----
    bn_reduce_lds(st1, g1_, be1_, sc_l, sh_l, blk_s, blk_q);
    __syncthreads();
    bn_relu_xa(xa, sc_l, sh_l);
    __syncthreads();
    layer_mfma_xa(xa, wb, blk_s, blk_q, Wbf + 2 * CC * CC, b2_, st2);
    grid.sync();

    // ---- phase 3: final BN(st2) + ReLU -> out (fp32) ----
    bn_reduce_lds(st2, g2_, be2_, sc_l, sh_l, blk_s, blk_q);
    __syncthreads();
#pragma unroll
    for (int e = threadIdx.x; e < 64 * 16; e += 256) {
        const int r = e >> 4, c8 = e & 15;
        const uint4 u = *(const uint4*)&xa[r][c8 * 8];
        const float4 s0 = *(const float4*)&sc_l[c8 * 8];
        const float4 s1 = *(const float4*)&sc_l[c8 * 8 + 4];
        const float4 h0 = *(const float4*)&sh_l[c8 * 8];
        const float4 h1 = *(const float4*)&sh_l[c8 * 8 + 4];
        float4 o0, o1;
        o0.x = fmaxf(fmaf(bflo(u.x), s0.x, h0.x), 0.f);
        o0.y = fmaxf(fmaf(bfhi(u.x), s0.y, h0.y), 0.f);
        o0.z = fmaxf(fmaf(bflo(u.y), s0.z, h0.z), 0.f);
        o0.w = fmaxf(fmaf(bfhi(u.y), s0.w, h0.w), 0.f);
        o1.x = fmaxf(fmaf(bflo(u.z), s1.x, h1.x), 0.f);
        o1.y = fmaxf(fmaf(bfhi(u.z), s1.y, h1.y), 0.f);
        o1.z = fmaxf(fmaf(bflo(u.w), s1.z, h1.z), 0.f);
        o1.w = fmaxf(fmaf(bfhi(u.w), s1.w, h1.w), 0.f);
        float4* op = (float4*)&out[(size_t)(row0 + r) * CC + c8 * 8];
        op[0] = o0; op[1] = o1;
    }
}

// ---------------------------------------------------------------------------
// Fallback path (non-cooperative): original per-layer kernels via global
// activation buffers. Used only if the cooperative launch cannot run.
// ---------------------------------------------------------------------------
template <int MODE>
__global__ __launch_bounds__(256) void gemm_mfma(const void* __restrict__ Xsrc_,
                                                 const unsigned* __restrict__ skeys,
                                                 const float* __restrict__ pos1,
                                                 const float4* __restrict__ pos2f4,
                                                 const float* __restrict__ statsIn,
                                                 const float* __restrict__ gIn,
                                                 const float* __restrict__ beIn,
                                                 const ushort_t* __restrict__ Wb,
                                                 const float* __restrict__ bias,
                                                 ushort_t* __restrict__ Y,
                                                 float* __restrict__ statsOut) {
    __shared__ __align__(16) short xa[64][136];
    __shared__ __align__(16) short wb[128][136];
    __shared__ __align__(16) float blk_s[CC], blk_q[CC];
    __shared__ __align__(16) float sc_l[CC], sh_l[CC];
    __shared__ int   lidx[QB][3];
    __shared__ float lw[QB][3];

    const int row0 = blockIdx.x * 64;

    if constexpr (MODE == 0) {
        rerank_interp_stage((const float*)Xsrc_, skeys, pos1, pos2f4, row0,
                            xa, wb, lidx, lw, blk_s, blk_q);
    } else {
        const ushort_t* Xbf = (const ushort_t*)Xsrc_;
        bn_reduce_lds(statsIn, gIn, beIn, sc_l, sh_l, blk_s, blk_q);
        __syncthreads();
#pragma unroll
        for (int e = threadIdx.x; e < 64 * 16; e += 256) {
            const int r = e >> 4, c8 = e & 15;
            const uint4 u = *(const uint4*)&Xbf[(size_t)(row0 + r) * CC + c8 * 8];
            const float4 s0 = *(const float4*)&sc_l[c8 * 8];
            const float4 s1 = *(const float4*)&sc_l[c8 * 8 + 4];
            const float4 h0 = *(const float4*)&sh_l[c8 * 8];
            const float4 h1 = *(const float4*)&sh_l[c8 * 8 + 4];
            const float v0 = fmaxf(fmaf(bflo(u.x), s0.x, h0.x), 0.f);
            const float v1 = fmaxf(fmaf(bfhi(u.x), s0.y, h0.y), 0.f);
            const float v2 = fmaxf(fmaf(bflo(u.y), s0.z, h0.z), 0.f);
            const float v3 = fmaxf(fmaf(bfhi(u.y), s0.w, h0.w), 0.f);
            const float v4 = fmaxf(fmaf(bflo(u.z), s1.x, h1.x), 0.f);
            const float v5 = fmaxf(fmaf(bfhi(u.z), s1.y, h1.y), 0.f);
            const float v6 = fmaxf(fmaf(bflo(u.w), s1.z, h1.z), 0.f);
            const float v7 = fmaxf(fmaf(bfhi(u.w), s1.w, h1.w), 0.f);
            uint4 o;
            o.x = bf16pair(v0, v1); o.y = bf16pair(v2, v3);
            o.z = bf16pair(v4, v5); o.w = bf16pair(v6, v7);
            *(uint4*)&xa[r][c8 * 8] = o;
        }
    }
    layer_mfma_xa(xa, wb, blk_s, blk_q, Wb, bias, statsOut);
    // export activation tile to global for the next (separate) kernel
    __syncthreads();
#pragma unroll
    for (int e = threadIdx.x; e < 64 * 16; e += 256) {
        const int r = e >> 4, c8 = e & 15;
        *(uint4*)&Y[(size_t)(row0 + r) * CC + c8 * 8] = *(const uint4*)&xa[r][c8 * 8];
    }
}

__global__ __launch_bounds__(256) void bn_final(const ushort_t* __restrict__ Y,
                                                const float* __restrict__ statsIn,
                                                const float* __restrict__ g,
                                                const float* __restrict__ be,
                                                float* __restrict__ out) {
    __shared__ __align__(16) float sc_l[CC], sh_l[CC];
    __shared__ float dum_s[CC], dum_q[CC];
    bn_reduce_lds(statsIn, g, be, sc_l, sh_l, dum_s, dum_q);
    __syncthreads();
    const int base = blockIdx.x * 1024 + threadIdx.x;   // 8-col group index
#pragma unroll
    for (int it = 0; it < 4; ++it) {
        const int i8 = base + it * 256;
        const int c8 = (i8 & 15) * 8;
        const uint4 u = *(const uint4*)&Y[(size_t)i8 * 8];
        const float4 s0 = *(const float4*)&sc_l[c8];
        const float4 s1 = *(const float4*)&sc_l[c8 + 4];
        const float4 h0 = *(const float4*)&sh_l[c8];
        const float4 h1 = *(const float4*)&sh_l[c8 + 4];
        float4 o0, o1;
        o0.x = fmaxf(fmaf(bflo(u.x), s0.x, h0.x), 0.f);
        o0.y = fmaxf(fmaf(bfhi(u.x), s0.y, h0.y), 0.f);
        o0.z = fmaxf(fmaf(bflo(u.y), s0.z, h0.z), 0.f);
        o0.w = fmaxf(fmaf(bfhi(u.y), s0.w, h0.w), 0.f);
        o1.x = fmaxf(fmaf(bflo(u.z), s1.x, h1.x), 0.f);
        o1.y = fmaxf(fmaf(bfhi(u.z), s1.y, h1.y), 0.f);
        o1.z = fmaxf(fmaf(bflo(u.w), s1.z, h1.z), 0.f);
        o1.w = fmaxf(fmaf(bfhi(u.w), s1.w, h1.w), 0.f);
        ((float4*)out)[i8 * 2 + 0] = o0;
        ((float4*)out)[i8 * 2 + 1] = o1;
    }
}

// ---------------------------------------------------------------------------
extern "C" void kernel_launch(void* const* d_in, const int* in_sizes, int n_in,
                              void* d_out, int out_size, void* d_ws, size_t ws_size,
                              hipStream_t stream) {
    (void)in_sizes; (void)n_in; (void)out_size; (void)ws_size;

    const float* pos1  = (const float*)d_in[0];
    const float* pos2  = (const float*)d_in[1];
    const float* feat2 = (const float*)d_in[2];
    const float* Wl[3]  = {(const float*)d_in[3], (const float*)d_in[7],  (const float*)d_in[11]};
    const float* bl[3]  = {(const float*)d_in[4], (const float*)d_in[8],  (const float*)d_in[12]};
    const float* gl[3]  = {(const float*)d_in[5], (const float*)d_in[9],  (const float*)d_in[13]};
    const float* bel[3] = {(const float*)d_in[6], (const float*)d_in[10], (const float*)d_in[14]};

    // Workspace layout
    float* ws = (float*)d_ws;
    ushort_t* B0 = (ushort_t*)ws;                   // NQ*CC bf16 (8 MB, fallback only)
    ushort_t* B1 = B0 + (size_t)NQ * CC;            // NQ*CC bf16 (8 MB, fallback only)
    unsigned* skeys = (unsigned*)(B1 + (size_t)NQ * CC);   // NQ*48 u32 (6 MB)
    float* stats = (float*)(skeys + (size_t)NQ * NSURV);   // 3*NGRP*256 floats
    ushort_t* Wbf = (ushort_t*)(stats + 3 * NGRP * 256);   // 3*16384 bf16
    uint4* ptile = (uint4*)(Wbf + 3 * CC * CC);            // (256+2)*64 uint4 (264 KB)
    float4* pos2f4 = (float4*)(ptile + (size_t)258 * 64);  // MC*16 B (128 KB)

    float* st0 = stats + 0 * NGRP * 256;
    float* st1 = stats + 1 * NGRP * 256;
    float* st2 = stats + 2 * NGRP * 256;
    float* outp = (float*)d_out;

    // 0: pack pos2 -> MFMA tiles + float4 copy (precedes knn/gemm)
    pack_kernel<<<MC / TB, TB, 0, stream>>>(pos2, ptile, pos2f4);
    // 1: KNN scan + W bf16 prep + stats zero
    knn_kernel<<<KNN_B + 16, TB, 0, stream>>>(pos1, ptile, skeys,
                                              Wl[0], Wl[1], Wl[2], Wbf, stats);

    // 2: fused MLP chain (cooperative) or 4-kernel fallback
    static int coop_ok = -1;
    if (coop_ok < 0) {
        int nb = 0;
        hipError_t e = hipOccupancyMaxActiveBlocksPerMultiprocessor(&nb, gemm_fused, 256, 0);
        coop_ok = (e == hipSuccess && nb >= 2) ? 1 : 0;   // need 512 co-resident on 256 CUs
    }
    bool launched = false;
    if (coop_ok == 1) {
        void* f2 = (void*)feat2;  void* sk = (void*)skeys;
        void* p1 = (void*)pos1;   void* p2 = (void*)pos2f4;
        void* wb_ = (void*)Wbf;
        void* a_b0 = (void*)bl[0];  void* a_b1 = (void*)bl[1];  void* a_b2 = (void*)bl[2];
        void* a_g0 = (void*)gl[0];  void* a_g1 = (void*)gl[1];  void* a_g2 = (void*)gl[2];
        void* a_e0 = (void*)bel[0]; void* a_e1 = (void*)bel[1]; void* a_e2 = (void*)bel[2];
        void* a_s0 = (void*)st0;    void* a_s1 = (void*)st1;    void* a_s2 = (void*)st2;
        void* a_o  = (void*)outp;
        void* args[] = {&f2, &sk, &p1, &p2, &wb_,
                        &a_b0, &a_b1, &a_b2, &a_g0, &a_g1, &a_g2,
                        &a_e0, &a_e1, &a_e2, &a_s0, &a_s1, &a_s2, &a_o};
        hipError_t e = hipLaunchCooperativeKernel((void*)gemm_fused, dim3(GEMM_B), dim3(256),
                                                  args, 0, stream);
        if (e == hipSuccess) launched = true; else coop_ok = 0;
    }
    if (!launched) {
        gemm_mfma<0><<<GEMM_B, 256, 0, stream>>>(feat2, skeys, pos1, pos2f4,
                                                 nullptr, nullptr, nullptr,
                                                 Wbf + 0 * CC * CC, bl[0], B0, st0);
        gemm_mfma<1><<<GEMM_B, 256, 0, stream>>>(B0, nullptr, nullptr, nullptr,
                                                 st0, gl[0], bel[0],
                                                 Wbf + 1 * CC * CC, bl[1], B1, st1);
        gemm_mfma<1><<<GEMM_B, 256, 0, stream>>>(B1, nullptr, nullptr, nullptr,
                                                 st1, gl[1], bel[1],
                                                 Wbf + 2 * CC * CC, bl[2], B0, st2);
        bn_final<<<GEMM_B, 256, 0, stream>>>(B0, st2, gl[2], bel[2], outp);
    }
}

// Round 12
// 189.113 us; speedup vs baseline: 1.0033x; 1.0033x over previous
//
#include <hip/hip_runtime.h>
#include <hip/hip_fp16.h>
#include <math.h>

// Problem constants (from reference)
#define NQ 32768   // query points (pos1)
#define MC 8192    // source points (pos2)
#define CC 128     // channels
#define EPS_BN 1e-5f
#define EPS_D  1e-8

#define DBL_BIG 1e300
#define IDX_BIG 0x7fffffff

// KNN config (R15 verified structure, unchanged)
#define QB  64          // queries per block (2 tiles of 32)
#define TB  256         // threads per block (4 waves)
#define PCE 2048        // piece of M per block
#define NT  32          // 32-cand tiles per wave (1024 cands)
#define KM7 0xFFFFFF80u     // scan keys: keep sign+exp+16 mant, low 7 = (t<<2)|r
#define KMASK 0xFFFFE000u   // dump keys: sign+exp+10 mant, low 13 = cand index
#define IMASK 0x1FFFu       // 13-bit index (M=8192)
#define NSURV 48            // survivors/query (4 pieces x 2 wh x 2 h x 3)
#define KNN_B ((NQ / QB) * 4)   // 2048 scan blocks
#define GEMM_B (NQ / 64)        // 512
#define NGRP 8                  // stats atomic groups (2048 addresses)

typedef __attribute__((ext_vector_type(8))) short bf16x8;     // 8 bf16
typedef __attribute__((ext_vector_type(8))) _Float16 half8;   // 8 f16
typedef __attribute__((ext_vector_type(4))) float floatx4;    // 16x16 acc
typedef __attribute__((ext_vector_type(16))) float floatx16;  // 32x32 acc
typedef unsigned short ushort_t;

// RNE fp32 -> bf16 pair packed in u32 (lo = a, hi = b)
__device__ __forceinline__ unsigned bf16pair(float a, float b) {
    unsigned ua = __float_as_uint(a); ua = (ua + 0x7FFFu + ((ua >> 16) & 1u)) >> 16;
    unsigned ub = __float_as_uint(b); ub = (ub + 0x7FFFu + ((ub >> 16) & 1u)) >> 16;
    return ua | (ub << 16);
}
__device__ __forceinline__ ushort_t bf16one(float a) {
    unsigned ua = __float_as_uint(a);
    return (ushort_t)((ua + 0x7FFFu + ((ua >> 16) & 1u)) >> 16);
}
// unpack u32 = (lo bf16, hi bf16) -> 2 fp32
__device__ __forceinline__ float bflo(unsigned u) { return __uint_as_float(u << 16); }
__device__ __forceinline__ float bfhi(unsigned u) { return __uint_as_float(u & 0xFFFF0000u); }

// Branchless insert of x into ascending top-3: 1x v_min_f32 + 2x v_med3_f32.
__device__ __forceinline__ void ins3(float& k0, float& k1, float& k2, float x) {
    const float n0 = fminf(k0, x);
    const float n1 = __builtin_amdgcn_fmed3f(k0, k1, x);
    const float n2 = __builtin_amdgcn_fmed3f(k1, k2, x);
    k0 = n0; k1 = n1; k2 = n2;
}

// Single-instruction (d & m) | ir with the mask held in an SGPR.
__device__ __forceinline__ unsigned vandor(unsigned d, unsigned m, unsigned ir) {
    unsigned r;
    asm("v_and_or_b32 %0, %1, %2, %3" : "=v"(r) : "v"(d), "s"(m), "v"(ir));
    return r;
}

// Hang-proof lightweight grid barrier (all blocks co-resident via cooperative
// launch). Monotonic counter; release add; POLL VIA ATOMIC RMW (+0) so the
// read always executes at the device-coherent point -- a stale-cache spin is
// impossible (per-XCD L2s are not coherent for plain loads). Bounded spin as
// a last-resort hang guard (never hit in normal operation).
__device__ __forceinline__ void gbar_sync(int* ctr, int target) {
    __syncthreads();
    if (threadIdx.x == 0) {
        __hip_atomic_fetch_add(ctr, 1, __ATOMIC_RELEASE, __HIP_MEMORY_SCOPE_AGENT);
        int it = 0;
        while (__hip_atomic_fetch_add(ctr, 0, __ATOMIC_ACQUIRE, __HIP_MEMORY_SCOPE_AGENT) < target) {
            __builtin_amdgcn_s_sleep(16);
            if (++it > (1 << 18)) break;   // ~0.1 s safety bound
        }
    }
    __syncthreads();
}

#define PK2(a, b) ((unsigned)__half_as_ushort(a) | ((unsigned)__half_as_ushort(b) << 16))

// ---------------------------------------------------------------------------
// Pack pos2 -> (a) 32x32x16 MFMA A-fragment tiles of split-f16 ext vectors,
//              (b) pos2f4: float4 {x,y,z,0} for the gemm rerank.
// Also zeroes the grid-barrier counter.
// ---------------------------------------------------------------------------
__global__ __launch_bounds__(TB) void pack_kernel(const float* __restrict__ pos2,
                                                  uint4* __restrict__ ptile,
                                                  float4* __restrict__ pos2f4,
                                                  int* __restrict__ gbar) {
    const int c = blockIdx.x * TB + threadIdx.x;   // grid 32 x 256 = 8192
    const float x = pos2[c * 3 + 0];
    const float y = pos2[c * 3 + 1];
    const float z = pos2[c * 3 + 2];
    float4 p4; p4.x = x; p4.y = y; p4.z = z; p4.w = 0.f;
    pos2f4[c] = p4;
    const __half chx = __float2half(x); const float fchx = __half2float(chx);
    const __half chy = __float2half(y); const float fchy = __half2float(chy);
    const __half chz = __float2half(z); const float fchz = __half2float(chz);
    const __half clx = __float2half(x - fchx);
    const __half cly = __float2half(y - fchy);
    const __half clz = __float2half(z - fchz);
    const double X = (double)fchx + (double)__half2float(clx);
    const double Y = (double)fchy + (double)__half2float(cly);
    const double Z = (double)fchz + (double)__half2float(clz);
    const double hc = 0.5 * (X * X + Y * Y + Z * Z);
    const __half hchi = __float2half((float)hc);
    const __half hclo = __float2half((float)(hc - (double)__half2float(hchi)));
    const __half one = __float2half(1.0f);
    uint4 a0, a1;
    a0.x = PK2(chx, chy); a0.y = PK2(chz, clx); a0.z = PK2(cly, clz); a0.w = PK2(chx, chy);
    a1.x = PK2(chz, clx); a1.y = PK2(cly, clz); a1.z = PK2(hchi, hclo); a1.w = PK2(one, one);
    const int t = c >> 5, m = c & 31;
    ptile[(size_t)t * 64 + m]      = a0;   // k 0..7
    ptile[(size_t)t * 64 + 32 + m] = a1;   // k 8..15
    if (blockIdx.x == 0 && threadIdx.x < 128) {   // 2 zero pad tiles
        uint4 zf = {0u, 0u, 0u, 0u};
        ptile[(size_t)256 * 64 + threadIdx.x] = zf;
    }
    if (blockIdx.x == 0 && threadIdx.x == 0) *gbar = 0;
}

// ---------------------------------------------------------------------------
// KNN scan (32x32 MFMA) + piggy-backed weight conversion + stats/barrier zero.
// (R15 verified, unchanged except gbar zeroing.)
// ---------------------------------------------------------------------------
__global__ __launch_bounds__(TB) void knn_kernel(const float* __restrict__ pos1,
                                                 const uint4* __restrict__ ptile,
                                                 unsigned* __restrict__ skeys,
                                                 const float* __restrict__ W0,
                                                 const float* __restrict__ W1,
                                                 const float* __restrict__ W2,
                                                 ushort_t* __restrict__ Wbf,
                                                 float* __restrict__ stats,
                                                 int* __restrict__ gbar) {
    __shared__ __align__(16) ushort_t qext[QB][16];   // 2 KB query ext vectors

    if (blockIdx.x >= KNN_B) {                 // ---- prep blocks ----
        const int pb = blockIdx.x - KNN_B;     // 0..15
        const int f = pb * TB + threadIdx.x;   // float4 index within a layer
        const float* Ws[3] = {W0, W1, W2};
#pragma unroll
        for (int l = 0; l < 3; ++l) {
            const float4 v = ((const float4*)Ws[l])[f];
            unsigned* dst = (unsigned*)(Wbf + (size_t)l * CC * CC);
            dst[f * 2 + 0] = bf16pair(v.x, v.y);
            dst[f * 2 + 1] = bf16pair(v.z, v.w);
        }
        if (pb == 0) {
            for (int i = threadIdx.x; i < 3 * NGRP * 256; i += TB) stats[i] = 0.f;
            if (threadIdx.x == 0) *gbar = 0;
        }
        return;
    }

    const int piece = blockIdx.x & 3;
    const int bq    = blockIdx.x >> 2;

    // ---- query ext staging ----
    if (threadIdx.x < QB) {
        const int qq = bq * QB + threadIdx.x;
        const float x = pos1[qq * 3 + 0];
        const float y = pos1[qq * 3 + 1];
        const float z = pos1[qq * 3 + 2];
        const __half phx = __float2half(x); const float fphx = __half2float(phx);
        const __half phy = __float2half(y); const float fphy = __half2float(phy);
        const __half phz = __float2half(z); const float fphz = __half2float(phz);
        const __half plx = __float2half(x - fphx);
        const __half ply = __float2half(y - fphy);
        const __half plz = __float2half(z - fphz);
        const double X = (double)fphx + (double)__half2float(plx);
        const double Y = (double)fphy + (double)__half2float(ply);
        const double Z = (double)fphz + (double)__half2float(plz);
        const double hp = 0.5 * (X * X + Y * Y + Z * Z);
        const __half hphi = __float2half((float)hp);
        const __half hplo = __float2half((float)(hp - (double)__half2float(hphi)));
        const ushort_t SG = 0x8000u;   // f16 sign flip = exact negation
        const ushort_t nx = (ushort_t)(__half_as_ushort(phx) ^ SG);
        const ushort_t ny = (ushort_t)(__half_as_ushort(phy) ^ SG);
        const ushort_t nz = (ushort_t)(__half_as_ushort(phz) ^ SG);
        const ushort_t mx = (ushort_t)(__half_as_ushort(plx) ^ SG);
        const ushort_t my = (ushort_t)(__half_as_ushort(ply) ^ SG);
        const ushort_t mz = (ushort_t)(__half_as_ushort(plz) ^ SG);
        const ushort_t on = __half_as_ushort(__float2half(1.0f));
        ushort_t* e = &qext[threadIdx.x][0];
        e[0] = nx; e[1] = ny; e[2] = nz; e[3] = nx; e[4]  = ny; e[5]  = nz;
        e[6] = mx; e[7] = my; e[8] = mz; e[9] = mx; e[10] = my; e[11] = mz;
        e[12] = on; e[13] = on;
        e[14] = __half_as_ushort(hphi); e[15] = __half_as_ushort(hplo);
    }
    __syncthreads();

    const int lane = threadIdx.x & 63;
    const int w    = threadIdx.x >> 6;
    const int qt   = w >> 1;            // query tile (0/1)
    const int wh   = w & 1;             // candidate half within piece
    const int col  = lane & 31;         // query column / candidate row
    const int h    = lane >> 5;         // k-slice (0/1)

    const uint4 bqu = *(const uint4*)&qext[qt * 32 + col][h * 8];
    const half8 bqh = *(const half8*)&bqu;

    const int cw = piece * PCE + wh * 1024;   // wave's candidate base
    const uint4* lp = ptile + (size_t)(cw >> 5) * 64 + h * 32 + col;
#define LD(t) lp[(size_t)(t) * 64]

    const float KINIT = __uint_as_float(0x7F000000u);   // large finite sentinel
    float a0 = KINIT, a1 = KINIT, a2 = KINIT;   // 4 independent top-3 chains
    float b0 = KINIT, b1 = KINIT, b2 = KINIT;
    float c0 = KINIT, c1 = KINIT, c2 = KINIT;
    float e0 = KINIT, e1 = KINIT, e2 = KINIT;
    unsigned i0 = 0u, i1 = 1u, i2 = 2u, i3 = 3u;
    const unsigned km7 = KM7;   // pinned to SGPR by the asm "s" constraint
    const floatx16 zc = {0.f,0.f,0.f,0.f,0.f,0.f,0.f,0.f,0.f,0.f,0.f,0.f,0.f,0.f,0.f,0.f};

#define KEY1(v, ir, K0, K1, K2) { \
        const unsigned u_ = vandor(__float_as_uint(v), km7, ir); \
        ins3(K0, K1, K2, __uint_as_float(u_)); }
#define KEYS(d) { \
        KEY1(d[0],  i0, a0, a1, a2); KEY1(d[1],  i1, a0, a1, a2); \
        KEY1(d[2],  i2, a0, a1, a2); KEY1(d[3],  i3, a0, a1, a2); \
        KEY1(d[4],  i0, b0, b1, b2); KEY1(d[5],  i1, b0, b1, b2); \
        KEY1(d[6],  i2, b0, b1, b2); KEY1(d[7],  i3, b0, b1, b2); \
        KEY1(d[8],  i0, c0, c1, c2); KEY1(d[9],  i1, c0, c1, c2); \
        KEY1(d[10], i2, c0, c1, c2); KEY1(d[11], i3, c0, c1, c2); \
        KEY1(d[12], i0, e0, e1, e2); KEY1(d[13], i1, e0, e1, e2); \
        KEY1(d[14], i2, e0, e1, e2); KEY1(d[15], i3, e0, e1, e2); \
        i0 += 4u; i1 += 4u; i2 += 4u; i3 += 4u; }

    uint4 LA = LD(0);
    uint4 LB = LD(1);
    for (int t = 0; t < NT; t += 2) {
        const floatx16 dv = __builtin_amdgcn_mfma_f32_32x32x16_f16(*(const half8*)&LA, bqh, zc, 0, 0, 0);
        LA = LD(t + 2);   // overshoots into pad tiles on last iter
        KEYS(dv);
        const floatx16 dw = __builtin_amdgcn_mfma_f32_32x32x16_f16(*(const half8*)&LB, bqh, zc, 0, 0, 0);
        LB = LD(t + 3);
        KEYS(dw);
    }
#undef LD
#undef KEYS
#undef KEY1

#define REKEY(kf, q) __uint_as_float((__float_as_uint(kf) & KMASK) | \
        (unsigned)(cw + (int)((__float_as_uint(kf) & 0x7Fu) >> 2) * 32 + \
                   (int)(__float_as_uint(kf) & 3u) + 8 * (q) + 4 * h))
    float m0 = KINIT, m1 = KINIT, m2 = KINIT;
    ins3(m0, m1, m2, REKEY(a0, 0)); ins3(m0, m1, m2, REKEY(a1, 0)); ins3(m0, m1, m2, REKEY(a2, 0));
    ins3(m0, m1, m2, REKEY(b0, 1)); ins3(m0, m1, m2, REKEY(b1, 1)); ins3(m0, m1, m2, REKEY(b2, 1));
    ins3(m0, m1, m2, REKEY(c0, 2)); ins3(m0, m1, m2, REKEY(c1, 2)); ins3(m0, m1, m2, REKEY(c2, 2));
    ins3(m0, m1, m2, REKEY(e0, 3)); ins3(m0, m1, m2, REKEY(e1, 3)); ins3(m0, m1, m2, REKEY(e2, 3));
#undef REKEY

    {
        const int q = bq * QB + qt * 32 + col;
        unsigned* dst = skeys + (size_t)q * NSURV + piece * 12 + wh * 6 + h * 3;
        dst[0] = __float_as_uint(m0);
        dst[1] = __float_as_uint(m1);
        dst[2] = __float_as_uint(m2);
    }
}

// ===========================================================================
// Shared device helpers for the GEMM side (used by fused and fallback paths)
// ===========================================================================

// Exact fp64 re-rank + interp staging into xa (bf16). Uses xa/wb as scratch.
__device__ __forceinline__ void rerank_interp_stage(
    const float* __restrict__ feat2, const unsigned* __restrict__ skeys,
    const float* __restrict__ pos1, const float4* __restrict__ pos2f4,
    int row0, short (*xa)[136], short (*wb)[136],
    int (*lidx)[3], float (*lw)[3], float* blk_s, float* blk_q)
{
    {   // exact fp64 re-rank of this block's 64 queries; 4 thr/query
        double* rrd = (double*)&xa[0][0];   // [64][4][3] = 6144 B scratch
        int*    rri = (int*)&wb[0][0];      // [64][4][3] = 3072 B scratch
        const int ql = threadIdx.x >> 2;
        const int pp = threadIdx.x & 3;
        const int qg = row0 + ql;
        const double qx = (double)pos1[qg * 3 + 0];
        const double qy = (double)pos1[qg * 3 + 1];
        const double qz = (double)pos1[qg * 3 + 2];
        double b0 = DBL_BIG, b1 = DBL_BIG, b2 = DBL_BIG;
        int    j0 = IDX_BIG, j1 = IDX_BIG, j2 = IDX_BIG;
        const uint4* kp = (const uint4*)(skeys + (size_t)qg * NSURV + pp * 12);
#pragma unroll
        for (int gi = 0; gi < 3; ++gi) {
            const uint4 kk = kp[gi];
            const unsigned ks[4] = {kk.x, kk.y, kk.z, kk.w};
#pragma unroll
            for (int u = 0; u < 4; ++u) {
                const int id = (int)(ks[u] & IMASK);
                const float4 cf = pos2f4[id];   // one aligned 16B load
                const double x = (double)cf.x;
                const double y = (double)cf.y;
                const double z = (double)cf.z;
                const double ax = qx - x, ay = qy - y, az = qz - z;
                const double d = ax * ax + ay * ay + az * az;
                const bool l2 = (d < b2) || (d == b2 && id < j2);
                if (l2) {
                    const bool l1 = (d < b1) || (d == b1 && id < j1);
                    const bool l0 = (d < b0) || (d == b0 && id < j0);
                    b2 = l1 ? b1 : d;              j2 = l1 ? j1 : id;
                    b1 = l1 ? (l0 ? b0 : d) : b1;  j1 = l1 ? (l0 ? j0 : id) : j1;
                    b0 = l0 ? d : b0;              j0 = l0 ? id : j0;
                }
            }
        }
        const int base = (ql * 4 + pp) * 3;
        rrd[base + 0] = b0; rri[base + 0] = j0;
        rrd[base + 1] = b1; rri[base + 1] = j1;
        rrd[base + 2] = b2; rri[base + 2] = j2;
        __syncthreads();
        if (threadIdx.x < QB) {
            const int qq = threadIdx.x;
            double c0 = DBL_BIG, c1 = DBL_BIG, c2 = DBL_BIG;
            int    i0 = IDX_BIG, i1 = IDX_BIG, i2 = IDX_BIG;
#pragma unroll
            for (int s = 0; s < 12; ++s) {
                const double d = rrd[qq * 12 + s];
                const int   id = rri[qq * 12 + s];
                const bool l2 = (d < c2) || (d == c2 && id < i2);
                if (l2) {
                    const bool l1 = (d < c1) || (d == c1 && id < i1);
                    const bool l0 = (d < c0) || (d == c0 && id < i0);
                    c2 = l1 ? c1 : d;              i2 = l1 ? i1 : id;
                    c1 = l1 ? (l0 ? c0 : d) : c1;  i1 = l1 ? (l0 ? i0 : id) : i1;
                    c0 = l0 ? d : c0;              i0 = l0 ? id : i0;
                }
            }
            const double r0 = 1.0 / (c0 + EPS_D);
            const double r1 = 1.0 / (c1 + EPS_D);
            const double r2 = 1.0 / (c2 + EPS_D);
            const double inv = 1.0 / (r0 + r1 + r2);
            lidx[qq][0] = i0; lidx[qq][1] = i1; lidx[qq][2] = i2;
            lw[qq][0] = (float)(r0 * inv);
            lw[qq][1] = (float)(r1 * inv);
            lw[qq][2] = (float)(r2 * inv);
        }
        __syncthreads();
    }
    if (threadIdx.x < CC) { blk_s[threadIdx.x] = 0.f; blk_q[threadIdx.x] = 0.f; }
#pragma unroll
    for (int e = threadIdx.x; e < 64 * 32; e += 256) {
        const int r = e >> 5, c4 = e & 31;
        const int i0 = lidx[r][0], i1 = lidx[r][1], i2 = lidx[r][2];
        const float w0 = lw[r][0], w1 = lw[r][1], w2 = lw[r][2];
        const float4 f0 = *(const float4*)&feat2[(size_t)i0 * CC + c4 * 4];
        const float4 f1 = *(const float4*)&feat2[(size_t)i1 * CC + c4 * 4];
        const float4 f2 = *(const float4*)&feat2[(size_t)i2 * CC + c4 * 4];
        float4 v;
        v.x = w0 * f0.x + w1 * f1.x + w2 * f2.x;
        v.y = w0 * f0.y + w1 * f1.y + w2 * f2.y;
        v.z = w0 * f0.z + w1 * f1.z + w2 * f2.z;
        v.w = w0 * f0.w + w1 * f1.w + w2 * f2.w;
        unsigned* dst = (unsigned*)&xa[r][0];
        dst[c4 * 2 + 0] = bf16pair(v.x, v.y);
        dst[c4 * 2 + 1] = bf16pair(v.z, v.w);
    }
}

// Reduce 8-group stats -> BN scale/shift in LDS; zero block stat accums.
// statsIn is read with agent-scope relaxed ATOMIC loads: values were produced
// by device-scope atomics in the previous phase; RMW/atomic reads execute at
// the coherent point, so no stale-L2 hazard across XCDs.
__device__ __forceinline__ void bn_reduce_lds(const float* __restrict__ statsIn,
                                              const float* __restrict__ g,
                                              const float* __restrict__ be,
                                              float* sc_l, float* sh_l,
                                              float* blk_s, float* blk_q)
{
    if (threadIdx.x < CC) {
        const int c = threadIdx.x;
        float s = 0.f, q = 0.f;
#pragma unroll
        for (int gr = 0; gr < NGRP; ++gr) {
            s += __hip_atomic_load(&statsIn[gr * 256 + c], __ATOMIC_RELAXED,
                                   __HIP_MEMORY_SCOPE_AGENT);
            q += __hip_atomic_load(&statsIn[gr * 256 + CC + c], __ATOMIC_RELAXED,
                                   __HIP_MEMORY_SCOPE_AGENT);
        }
        const float m = s * (1.f / (float)NQ);
        const float v = fmaf(-m, m, q * (1.f / (float)NQ));
        const float rstd = rsqrtf(v + EPS_BN);
        const float scl = g[c] * rstd;
        sc_l[c] = scl;
        sh_l[c] = fmaf(-m, scl, be[c]);
        blk_s[c] = 0.f; blk_q[c] = 0.f;
    }
}

// Apply BN+ReLU in place to the LDS activation tile (bf16).
__device__ __forceinline__ void bn_relu_xa(short (*xa)[136],
                                           const float* sc_l, const float* sh_l)
{
#pragma unroll
    for (int e = threadIdx.x; e < 64 * 16; e += 256) {
        const int r = e >> 4, c8 = e & 15;
        const uint4 u = *(const uint4*)&xa[r][c8 * 8];
        const float4 s0 = *(const float4*)&sc_l[c8 * 8];
        const float4 s1 = *(const float4*)&sc_l[c8 * 8 + 4];
        const float4 h0 = *(const float4*)&sh_l[c8 * 8];
        const float4 h1 = *(const float4*)&sh_l[c8 * 8 + 4];
        const float v0 = fmaxf(fmaf(bflo(u.x), s0.x, h0.x), 0.f);
        const float v1 = fmaxf(fmaf(bfhi(u.x), s0.y, h0.y), 0.f);
        const float v2 = fmaxf(fmaf(bflo(u.y), s0.z, h0.z), 0.f);
        const float v3 = fmaxf(fmaf(bfhi(u.y), s0.w, h0.w), 0.f);
        const float v4 = fmaxf(fmaf(bflo(u.z), s1.x, h1.x), 0.f);
        const float v5 = fmaxf(fmaf(bfhi(u.z), s1.y, h1.y), 0.f);
        const float v6 = fmaxf(fmaf(bflo(u.w), s1.z, h1.z), 0.f);
        const float v7 = fmaxf(fmaf(bfhi(u.w), s1.w, h1.w), 0.f);
        uint4 o;
        o.x = bf16pair(v0, v1); o.y = bf16pair(v2, v3);
        o.z = bf16pair(v4, v5); o.w = bf16pair(v6, v7);
        *(uint4*)&xa[r][c8 * 8] = o;
    }
}

// One MFMA layer on the LDS-resident X tile: stage W, GEMM, write result
// (bias-added, bf16) back into xa, accumulate column stats into statsOut.
__device__ __forceinline__ void layer_mfma_xa(short (*xa)[136], short (*wb)[136],
                                              float* blk_s, float* blk_q,
                                              const ushort_t* __restrict__ Wb,
                                              const float* __restrict__ bias,
                                              float* __restrict__ statsOut)
{
#pragma unroll
    for (int e = threadIdx.x; e < 128 * 16; e += 256) {
        const int co = e >> 4, seg = e & 15;
        *(float4*)&wb[co][seg * 8] = *(const float4*)&Wb[(size_t)co * CC + seg * 8];
    }
    __syncthreads();

    const int lane = threadIdx.x & 63;
    const int wv = threadIdx.x >> 6;
    const int nn = lane & 15;
    const int quad = lane >> 4;

    floatx4 acc[8] = {};
    const short* arow = &xa[wv * 16 + nn][0];
#pragma unroll
    for (int ks = 0; ks < 4; ++ks) {
        const bf16x8 a = *(const bf16x8*)(arow + ks * 32 + quad * 8);
#pragma unroll
        for (int ct = 0; ct < 8; ++ct) {
            const bf16x8 b = *(const bf16x8*)(&wb[ct * 16 + nn][0] + ks * 32 + quad * 8);
            acc[ct] = __builtin_amdgcn_mfma_f32_16x16x32_bf16(a, b, acc[ct], 0, 0, 0);
        }
    }
    __syncthreads();   // drain all xa reads before overwriting in place
#pragma unroll
    for (int ct = 0; ct < 8; ++ct) {
        const float bv = bias[ct * 16 + nn];
        float s = 0.f, qv = 0.f;
#pragma unroll
        for (int r = 0; r < 4; ++r) {
            acc[ct][r] += bv;
            s += acc[ct][r];
            qv = fmaf(acc[ct][r], acc[ct][r], qv);
        }
#pragma unroll
        for (int r = 0; r < 4; ++r)
            xa[wv * 16 + quad * 4 + r][ct * 16 + nn] = (short)bf16one(acc[ct][r]);
        s += __shfl_xor(s, 16, 64); s += __shfl_xor(s, 32, 64);
        qv += __shfl_xor(qv, 16, 64); qv += __shfl_xor(qv, 32, 64);
        if (quad == 0) {
            atomicAdd(&blk_s[ct * 16 + nn], s);
            atomicAdd(&blk_q[ct * 16 + nn], qv);
        }
    }
    __syncthreads();
    {
        const int ch = threadIdx.x;
        const float v = (ch < CC) ? blk_s[ch] : blk_q[ch - CC];
        atomicAdd(&statsOut[(blockIdx.x & (NGRP - 1)) * 256 + ch], v);
    }
}

// ---------------------------------------------------------------------------
// Fused MLP chain (cooperative launch, hang-proof lightweight grid barrier):
// rerank+interp+L0 -> bar -> BN+L1 -> bar -> BN+L2 -> bar -> BN-final -> out.
// Activation tile stays in LDS throughout. grid = 512 x 256 (2 blocks/CU).
// ---------------------------------------------------------------------------
__global__ __launch_bounds__(256) void gemm_fused(
        const float* __restrict__ feat2, const unsigned* __restrict__ skeys,
        const float* __restrict__ pos1, const float4* __restrict__ pos2f4,
        const ushort_t* __restrict__ Wbf,
        const float* __restrict__ b0_, const float* __restrict__ b1_, const float* __restrict__ b2_,
        const float* __restrict__ g0_, const float* __restrict__ g1_, const float* __restrict__ g2_,
        const float* __restrict__ be0_, const float* __restrict__ be1_, const float* __restrict__ be2_,
        float* __restrict__ st0, float* __restrict__ st1, float* __restrict__ st2,
        int* __restrict__ gbar,
        float* __restrict__ out)
{
    __shared__ __align__(16) short xa[64][136];
    __shared__ __align__(16) short wb[128][136];
    __shared__ __align__(16) float blk_s[CC], blk_q[CC];
    __shared__ __align__(16) float sc_l[CC], sh_l[CC];
    __shared__ int   lidx[QB][3];
    __shared__ float lw[QB][3];

    const int row0 = blockIdx.x * 64;

    // ---- phase 0: rerank + interp -> xa; GEMM layer 0 -> xa, st0 ----
    rerank_interp_stage(feat2, skeys, pos1, pos2f4, row0, xa, wb, lidx, lw, blk_s, blk_q);
    layer_mfma_xa(xa, wb, blk_s, blk_q, Wbf + 0 * CC * CC, b0_, st0);
    gbar_sync(gbar, GEMM_B);

    // ---- phase 1: BN(st0) + ReLU on xa; GEMM layer 1 -> xa, st1 ----
    bn_reduce_lds(st0, g0_, be0_, sc_l, sh_l, blk_s, blk_q);
    __syncthreads();
    bn_relu_xa(xa, sc_l, sh_l);
    __syncthreads();
    layer_mfma_xa(xa, wb, blk_s, blk_q, Wbf + 1 * CC * CC, b1_, st1);
    gbar_sync(gbar, 2 * GEMM_B);

    // ---- phase 2: BN(st1) + ReLU; GEMM layer 2 -> xa, st2 ----
    bn_reduce_lds(st1, g1_, be1_, sc_l, sh_l, blk_s, blk_q);
    __syncthreads();
    bn_relu_xa(xa, sc_l, sh_l);
    __syncthreads();
    layer_mfma_xa(xa, wb, blk_s, blk_q, Wbf + 2 * CC * CC, b2_, st2);
    gbar_sync(gbar, 3 * GEMM_B);

    // ---- phase 3: final BN(st2) + ReLU -> out (fp32) ----
    bn_reduce_lds(st2, g2_, be2_, sc_l, sh_l, blk_s, blk_q);
    __syncthreads();
#pragma unroll
    for (int e = threadIdx.x; e < 64 * 16; e += 256) {
        const int r = e >> 4, c8 = e & 15;
        const uint4 u = *(const uint4*)&xa[r][c8 * 8];
        const float4 s0 = *(const float4*)&sc_l[c8 * 8];
        const float4 s1 = *(const float4*)&sc_l[c8 * 8 + 4];
        const float4 h0 = *(const float4*)&sh_l[c8 * 8];
        const float4 h1 = *(const float4*)&sh_l[c8 * 8 + 4];
        float4 o0, o1;
        o0.x = fmaxf(fmaf(bflo(u.x), s0.x, h0.x), 0.f);
        o0.y = fmaxf(fmaf(bfhi(u.x), s0.y, h0.y), 0.f);
        o0.z = fmaxf(fmaf(bflo(u.y), s0.z, h0.z), 0.f);
        o0.w = fmaxf(fmaf(bfhi(u.y), s0.w, h0.w), 0.f);
        o1.x = fmaxf(fmaf(bflo(u.z), s1.x, h1.x), 0.f);
        o1.y = fmaxf(fmaf(bfhi(u.z), s1.y, h1.y), 0.f);
        o1.z = fmaxf(fmaf(bflo(u.w), s1.z, h1.z), 0.f);
        o1.w = fmaxf(fmaf(bfhi(u.w), s1.w, h1.w), 0.f);
        float4* op = (float4*)&out[(size_t)(row0 + r) * CC + c8 * 8];
        op[0] = o0; op[1] = o1;
    }
}

// ---------------------------------------------------------------------------
// Fallback path (non-cooperative): per-layer kernels via global buffers.
// ---------------------------------------------------------------------------
template <int MODE>
__global__ __launch_bounds__(256) void gemm_mfma(const void* __restrict__ Xsrc_,
                                                 const unsigned* __restrict__ skeys,
                                                 const float* __restrict__ pos1,
                                                 const float4* __restrict__ pos2f4,
                                                 const float* __restrict__ statsIn,
                                                 const float* __restrict__ gIn,
                                                 const float* __restrict__ beIn,
                                                 const ushort_t* __restrict__ Wb,
                                                 const float* __restrict__ bias,
                                                 ushort_t* __restrict__ Y,
                                                 float* __restrict__ statsOut) {
    __shared__ __align__(16) short xa[64][136];
    __shared__ __align__(16) short wb[128][136];
    __shared__ __align__(16) float blk_s[CC], blk_q[CC];
    __shared__ __align__(16) float sc_l[CC], sh_l[CC];
    __shared__ int   lidx[QB][3];
    __shared__ float lw[QB][3];

    const int row0 = blockIdx.x * 64;

    if constexpr (MODE == 0) {
        rerank_interp_stage((const float*)Xsrc_, skeys, pos1, pos2f4, row0,
                            xa, wb, lidx, lw, blk_s, blk_q);
    } else {
        const ushort_t* Xbf = (const ushort_t*)Xsrc_;
        bn_reduce_lds(statsIn, gIn, beIn, sc_l, sh_l, blk_s, blk_q);
        __syncthreads();
#pragma unroll
        for (int e = threadIdx.x; e < 64 * 16; e += 256) {
            const int r = e >> 4, c8 = e & 15;
            const uint4 u = *(const uint4*)&Xbf[(size_t)(row0 + r) * CC + c8 * 8];
            const float4 s0 = *(const float4*)&sc_l[c8 * 8];
            const float4 s1 = *(const float4*)&sc_l[c8 * 8 + 4];
            const float4 h0 = *(const float4*)&sh_l[c8 * 8];
            const float4 h1 = *(const float4*)&sh_l[c8 * 8 + 4];
            const float v0 = fmaxf(fmaf(bflo(u.x), s0.x, h0.x), 0.f);
            const float v1 = fmaxf(fmaf(bfhi(u.x), s0.y, h0.y), 0.f);
            const float v2 = fmaxf(fmaf(bflo(u.y), s0.z, h0.z), 0.f);
            const float v3 = fmaxf(fmaf(bfhi(u.y), s0.w, h0.w), 0.f);
            const float v4 = fmaxf(fmaf(bflo(u.z), s1.x, h1.x), 0.f);
            const float v5 = fmaxf(fmaf(bfhi(u.z), s1.y, h1.y), 0.f);
            const float v6 = fmaxf(fmaf(bflo(u.w), s1.z, h1.z), 0.f);
            const float v7 = fmaxf(fmaf(bfhi(u.w), s1.w, h1.w), 0.f);
            uint4 o;
            o.x = bf16pair(v0, v1); o.y = bf16pair(v2, v3);
            o.z = bf16pair(v4, v5); o.w = bf16pair(v6, v7);
            *(uint4*)&xa[r][c8 * 8] = o;
        }
    }
    layer_mfma_xa(xa, wb, blk_s, blk_q, Wb, bias, statsOut);
    __syncthreads();
#pragma unroll
    for (int e = threadIdx.x; e < 64 * 16; e += 256) {
        const int r = e >> 4, c8 = e & 15;
        *(uint4*)&Y[(size_t)(row0 + r) * CC + c8 * 8] = *(const uint4*)&xa[r][c8 * 8];
    }
}

__global__ __launch_bounds__(256) void bn_final(const ushort_t* __restrict__ Y,
                                                const float* __restrict__ statsIn,
                                                const float* __restrict__ g,
                                                const float* __restrict__ be,
                                                float* __restrict__ out) {
    __shared__ __align__(16) float sc_l[CC], sh_l[CC];
    __shared__ float dum_s[CC], dum_q[CC];
    bn_reduce_lds(statsIn, g, be, sc_l, sh_l, dum_s, dum_q);
    __syncthreads();
    const int base = blockIdx.x * 1024 + threadIdx.x;   // 8-col group index
#pragma unroll
    for (int it = 0; it < 4; ++it) {
        const int i8 = base + it * 256;
        const int c8 = (i8 & 15) * 8;
        const uint4 u = *(const uint4*)&Y[(size_t)i8 * 8];
        const float4 s0 = *(const float4*)&sc_l[c8];
        const float4 s1 = *(const float4*)&sc_l[c8 + 4];
        const float4 h0 = *(const float4*)&sh_l[c8];
        const float4 h1 = *(const float4*)&sh_l[c8 + 4];
        float4 o0, o1;
        o0.x = fmaxf(fmaf(bflo(u.x), s0.x, h0.x), 0.f);
        o0.y = fmaxf(fmaf(bfhi(u.x), s0.y, h0.y), 0.f);
        o0.z = fmaxf(fmaf(bflo(u.y), s0.z, h0.z), 0.f);
        o0.w = fmaxf(fmaf(bfhi(u.y), s0.w, h0.w), 0.f);
        o1.x = fmaxf(fmaf(bflo(u.z), s1.x, h1.x), 0.f);
        o1.y = fmaxf(fmaf(bfhi(u.z), s1.y, h1.y), 0.f);
        o1.z = fmaxf(fmaf(bflo(u.w), s1.z, h1.z), 0.f);
        o1.w = fmaxf(fmaf(bfhi(u.w), s1.w, h1.w), 0.f);
        ((float4*)out)[i8 * 2 + 0] = o0;
        ((float4*)out)[i8 * 2 + 1] = o1;
    }
}

// ---------------------------------------------------------------------------
extern "C" void kernel_launch(void* const* d_in, const int* in_sizes, int n_in,
                              void* d_out, int out_size, void* d_ws, size_t ws_size,
                              hipStream_t stream) {
    (void)in_sizes; (void)n_in; (void)out_size; (void)ws_size;

    const float* pos1  = (const float*)d_in[0];
    const float* pos2  = (const float*)d_in[1];
    const float* feat2 = (const float*)d_in[2];
    const float* Wl[3]  = {(const float*)d_in[3], (const float*)d_in[7],  (const float*)d_in[11]};
    const float* bl[3]  = {(const float*)d_in[4], (const float*)d_in[8],  (const float*)d_in[12]};
    const float* gl[3]  = {(const float*)d_in[5], (const float*)d_in[9],  (const float*)d_in[13]};
    const float* bel[3] = {(const float*)d_in[6], (const float*)d_in[10], (const float*)d_in[14]};

    // Workspace layout
    float* ws = (float*)d_ws;
    ushort_t* B0 = (ushort_t*)ws;                   // NQ*CC bf16 (8 MB, fallback only)
    ushort_t* B1 = B0 + (size_t)NQ * CC;            // NQ*CC bf16 (8 MB, fallback only)
    unsigned* skeys = (unsigned*)(B1 + (size_t)NQ * CC);   // NQ*48 u32 (6 MB)
    float* stats = (float*)(skeys + (size_t)NQ * NSURV);   // 3*NGRP*256 floats
    ushort_t* Wbf = (ushort_t*)(stats + 3 * NGRP * 256);   // 3*16384 bf16
    uint4* ptile = (uint4*)(Wbf + 3 * CC * CC);            // (256+2)*64 uint4 (264 KB)
    float4* pos2f4 = (float4*)(ptile + (size_t)258 * 64);  // MC*16 B (128 KB)
    int* gbar = (int*)(pos2f4 + MC) + 64;                  // barrier ctr (256B pad)

    float* st0 = stats + 0 * NGRP * 256;
    float* st1 = stats + 1 * NGRP * 256;
    float* st2 = stats + 2 * NGRP * 256;
    float* outp = (float*)d_out;

    // 0: pack pos2 -> MFMA tiles + float4 copy; zero barrier
    pack_kernel<<<MC / TB, TB, 0, stream>>>(pos2, ptile, pos2f4, gbar);
    // 1: KNN scan + W bf16 prep + stats/barrier zero
    knn_kernel<<<KNN_B + 16, TB, 0, stream>>>(pos1, ptile, skeys,
                                              Wl[0], Wl[1], Wl[2], Wbf, stats, gbar);

    // 2: fused MLP chain (cooperative launch, hardened barrier) or fallback
    static int coop_ok = -1;
    if (coop_ok < 0) {
        int nb = 0;
        hipError_t e = hipOccupancyMaxActiveBlocksPerMultiprocessor(&nb, gemm_fused, 256, 0);
        coop_ok = (e == hipSuccess && nb >= 2) ? 1 : 0;   // need 512 co-resident on 256 CUs
    }
    bool launched = false;
    if (coop_ok == 1) {
        void* f2 = (void*)feat2;  void* sk = (void*)skeys;
        void* p1 = (void*)pos1;   void* p2 = (void*)pos2f4;
        void* wb_ = (void*)Wbf;
        void* a_b0 = (void*)bl[0];  void* a_b1 = (void*)bl[1];  void* a_b2 = (void*)bl[2];
        void* a_g0 = (void*)gl[0];  void* a_g1 = (void*)gl[1];  void* a_g2 = (void*)gl[2];
        void* a_e0 = (void*)bel[0]; void* a_e1 = (void*)bel[1]; void* a_e2 = (void*)bel[2];
        void* a_s0 = (void*)st0;    void* a_s1 = (void*)st1;    void* a_s2 = (void*)st2;
        void* a_gb = (void*)gbar;   void* a_o  = (void*)outp;
        void* args[] = {&f2, &sk, &p1, &p2, &wb_,
                        &a_b0, &a_b1, &a_b2, &a_g0, &a_g1, &a_g2,
                        &a_e0, &a_e1, &a_e2, &a_s0, &a_s1, &a_s2, &a_gb, &a_o};
        hipError_t e = hipLaunchCooperativeKernel((void*)gemm_fused, dim3(GEMM_B), dim3(256),
                                                  args, 0, stream);
        if (e == hipSuccess) launched = true; else coop_ok = 0;
    }
    if (!launched) {
        gemm_mfma<0><<<GEMM_B, 256, 0, stream>>>(feat2, skeys, pos1, pos2f4,
                                                 nullptr, nullptr, nullptr,
                                                 Wbf + 0 * CC * CC, bl[0], B0, st0);
        gemm_mfma<1><<<GEMM_B, 256, 0, stream>>>(B0, nullptr, nullptr, nullptr,
                                                 st0, gl[0], bel[0],
                                                 Wbf + 1 * CC * CC, bl[1], B1, st1);
        gemm_mfma<1><<<GEMM_B, 256, 0, stream>>>(B1, nullptr, nullptr, nullptr,
                                                 st1, gl[1], bel[1],
                                                 Wbf + 2 * CC * CC, bl[2], B0, st2);
        bn_final<<<GEMM_B, 256, 0, stream>>>(B0, st2, gl[2], bel[2], outp);
    }
}